// Round 18
// baseline (425.062 us; speedup 1.0000x reference)
//
#include <hip/hip_runtime.h>
#include <hip/hip_fp16.h>

#define K_DIM 4096
#define N_DIM 11008
#define NZ8   1376          // N_DIM/8
#define BM    256
#define BN    256
#define NT_N  43            // N_DIM/BN
#define NKT   64            // K_DIM/64
#define ATB   32768         // A tile bytes = 256*64*2

typedef _Float16 f16x8 __attribute__((ext_vector_type(8)));
typedef float    f32x4 __attribute__((ext_vector_type(4)));

#define SB()    __builtin_amdgcn_sched_barrier(0)
#define BAR()   __builtin_amdgcn_s_barrier()
#define VMW(N)  do { asm volatile("s_waitcnt vmcnt(" #N ")" ::: "memory"); SB(); } while (0)
#define LGKM0() do { asm volatile("s_waitcnt lgkmcnt(0)" ::: "memory"); SB(); } while (0)

// 1 int32 -> 8 fp16 dequant, (k,k+4)-interleaved order
__device__ __forceinline__ f16x8 dq8(unsigned q, __half2 scp, __half2 nzp)
{
    const unsigned mu = 0xE400E400u;
    const __half2 m1024 = *(const __half2*)&mu;
    union { __half2 h2[4]; f16x8 v; } p;
#pragma unroll
    for (int d = 0; d < 4; ++d) {
        unsigned t = ((q >> (4 * d)) & 0x000F000Fu) | 0x64006400u;
        p.h2[d] = __hfma2(__hadd2(*(const __half2*)&t, m1024), scp, nzp);
    }
    return p.v;
}

// ---- pre-pass: x f32 -> fp16 ws, layout [mtile][ktile][kh][slot][row][16B]
// (identical to r13/r15; GEMM A-stage = linear global_load_lds, conflict-free)
__global__ __launch_bounds__(256)
void r18_xcvt(const float* __restrict__ x, __half* __restrict__ xh, int nchunks)
{
    int c = blockIdx.x * 256 + threadIdx.x;
    const int stride = gridDim.x * 256;
    for (; c < nchunks; c += stride) {
        const int row = c & 255;
        const int sl  = (c >> 8) & 3;
        const int kh  = (c >> 10) & 1;
        const int tl  = c >> 11;
        const int mt  = tl >> 6;
        const int kt  = tl & 63;
        const size_t gm = (size_t)mt * 256 + row;
        const int kb = kt * 64 + kh * 32 + sl * 8;
        const float4 f0 = *(const float4*)(x + gm * K_DIM + kb);
        const float4 f1 = *(const float4*)(x + gm * K_DIM + kb + 4);
        union { __half2 h2[4]; int4 v; } p;
        p.h2[0] = __floats2half2_rn(f0.x, f1.x);
        p.h2[1] = __floats2half2_rn(f0.y, f1.y);
        p.h2[2] = __floats2half2_rn(f0.z, f1.z);
        p.h2[3] = __floats2half2_rn(f0.w, f1.w);
        ((int4*)xh)[c] = p.v;
    }
}

// ---- ledger issue helpers (r13/r15-proven 64-bit-vaddr asm form) ----
#define ISSUE_Q8(D0,D1,D2,D3,D4,D5,D6,D7) do { \
    asm volatile( \
        "global_load_dword %0, %8, off\n\t" \
        "global_load_dword %1, %8, off offset:64\n\t" \
        "global_load_dword %2, %8, off offset:128\n\t" \
        "global_load_dword %3, %8, off offset:192\n\t" \
        "global_load_dword %4, %9, off\n\t" \
        "global_load_dword %5, %9, off offset:64\n\t" \
        "global_load_dword %6, %9, off offset:128\n\t" \
        "global_load_dword %7, %9, off offset:192" \
        : "=&v"(D0), "=&v"(D1), "=&v"(D2), "=&v"(D3), \
          "=&v"(D4), "=&v"(D5), "=&v"(D6), "=&v"(D7) \
        : "v"(qp0), "v"(qp1) : "memory"); \
    qp0 += 8 * N_DIM; qp1 += 8 * N_DIM; \
} while (0)

#define ISSUE_SZ() do { \
    asm volatile( \
        "global_load_dword %0, %8, off\n\t" \
        "global_load_dword %1, %8, off offset:64\n\t" \
        "global_load_dword %2, %8, off offset:128\n\t" \
        "global_load_dword %3, %8, off offset:192\n\t" \
        "global_load_dword %4, %9, off\n\t" \
        "global_load_dword %5, %9, off offset:8\n\t" \
        "global_load_dword %6, %9, off offset:16\n\t" \
        "global_load_dword %7, %9, off offset:24" \
        : "=&v"(sS0), "=&v"(sS1), "=&v"(sS2), "=&v"(sS3), \
          "=&v"(sZ0), "=&v"(sZ1), "=&v"(sZ2), "=&v"(sZ3) \
        : "v"(sp), "v"(zp) : "memory"); \
    sp += N_DIM; zp += NZ8; \
} while (0)

#define ISSUE_A(BUFP, T) do { \
    const char* _s = agp + (size_t)(T) * ATB; \
    _Pragma("unroll") for (int j = 0; j < 4; ++j) \
        __builtin_amdgcn_global_load_lds((const unsigned int*)(_s + j * 8192), \
            (unsigned int*)((BUFP) + j * 8192 + tid * 16), 16, 0, 0); \
} while (0)

#define FRAGS(ARp, KH) do { \
    _Pragma("unroll") for (int m = 0; m < 8; ++m) \
        af[m] = *(const f16x8*)((ARp) + (KH) * 16384 + aOff + m * 256); \
} while (0)

#define DQ4(Q0,Q1,Q2,Q3) do { \
    bf[0] = dq8(Q0, scp0, nzp0); bf[1] = dq8(Q1, scp1, nzp1); \
    bf[2] = dq8(Q2, scp2, nzp2); bf[3] = dq8(Q3, scp3, nzp3); \
} while (0)

#define MFMA32() do { \
    __builtin_amdgcn_s_setprio(1); \
    _Pragma("unroll") for (int m = 0; m < 8; ++m) \
        _Pragma("unroll") for (int n = 0; n < 4; ++n) \
            acc[m][n] = __builtin_amdgcn_mfma_f32_16x16x32_f16(af[m], bf[n], acc[m][n], 0, 0, 0); \
    __builtin_amdgcn_s_setprio(0); \
    SB(); \
} while (0)

#define CVT_S() do { \
    const float _s0 = __uint_as_float(sS0), _s1 = __uint_as_float(sS1); \
    const float _s2 = __uint_as_float(sS2), _s3 = __uint_as_float(sS3); \
    const __half _h0 = __float2half_rn(_s0), _h1 = __float2half_rn(_s1); \
    const __half _h2 = __float2half_rn(_s2), _h3 = __float2half_rn(_s3); \
    scp0 = __half2(_h0, _h0); scp1 = __half2(_h1, _h1); \
    scp2 = __half2(_h2, _h2); scp3 = __half2(_h3, _h3); \
    const __half _n0 = __float2half_rn(-_s0 * (float)((sZ0 >> sh4) & 15u)); \
    const __half _n1 = __float2half_rn(-_s1 * (float)((sZ1 >> sh4) & 15u)); \
    const __half _n2 = __float2half_rn(-_s2 * (float)((sZ2 >> sh4) & 15u)); \
    const __half _n3 = __float2half_rn(-_s3 * (float)((sZ3 >> sh4) & 15u)); \
    nzp0 = __half2(_n0, _n0); nzp1 = __half2(_n1, _n1); \
    nzp2 = __half2(_n2, _n2); nzp3 = __half2(_n3, _n3); \
} while (0)

#define SWAP_A() do { unsigned char* _tp = aR; aR = aW; aW = _tp; } while (0)

// ---- fused GEMM: 256x256, 8 waves (2Mx4N), MFMA 16x16x32, B dequant-to-reg.
// r18 = r15 dataflow + m201-style phase barriers per k-half:
//   FRAGS -> BAR -> DQ(VALU under ds latency) -> lgkm0 -> setprio MFMA -> BAR
// Counted-vmcnt ledger identical to r15 (VMW(12)/VMW(8), never 0 in steady).
__global__ __launch_bounds__(512, 2)
void r18_gemm(const __half* __restrict__ xh,
              const int*   __restrict__ qweight,
              const int*   __restrict__ qzeros,
              const float* __restrict__ scales,
              const float* __restrict__ bias,
              float* __restrict__ out)
{
    __shared__ __align__(16) unsigned char A0s[ATB], A1s[ATB];   // 64 KB

    const int tid  = threadIdx.x;
    const int lane = tid & 63;
    const int wid  = tid >> 6;
    const int wr   = (wid >> 2) * 128;   // wave M offset (0,128)
    const int wc   = (wid & 3) * 64;     // wave N offset (0,64,128,192)

    int bid = blockIdx.x;                // XCD swizzle (688 = 8*86)
    const int cpx = gridDim.x >> 3;
    bid = (bid & 7) * cpx + (bid >> 3);
    const int bm0 = (bid / NT_N) * BM;
    const int bn0 = (bid % NT_N) * BN;

    const int frow = lane & 15, kb8 = lane >> 4;
    const int ngl2 = bn0 + wc + frow;            // this lane's base column
    const int sh4  = (ngl2 & 7) * 4;
    const int aOff = kb8 * 4096 + (wr + frow) * 16;

    const char* agp = (const char*)xh + ((size_t)(bm0 >> 8) * NKT) * ATB + tid * 16;

    const int*   qp0 = qweight + (size_t)kb8 * N_DIM + ngl2;          // kh0 rows
    const int*   qp1 = qweight + (size_t)(kb8 + 4) * N_DIM + ngl2;    // kh1 rows
    const float* sp  = scales + (size_t)N_DIM + ngl2;                 // group 1
    const int*   zp  = qzeros + (size_t)NZ8 + (ngl2 >> 3);            // group 1

    unsigned char *aR = A0s, *aW = A1s;

    f32x4 acc[8][4];
#pragma unroll
    for (int m = 0; m < 8; ++m)
#pragma unroll
        for (int n = 0; n < 4; ++n)
            acc[m][n] = (f32x4){0.f, 0.f, 0.f, 0.f};
    f16x8 af[8], bf[4];
    __half2 scp0, scp1, scp2, scp3, nzp0, nzp1, nzp2, nzp3;
    unsigned qa0, qa1, qa2, qa3, qa4, qa5, qa6, qa7;
    unsigned qb0, qb1, qb2, qb3, qb4, qb5, qb6, qb7;
    unsigned sS0, sS1, sS2, sS3, sZ0, sZ1, sZ2, sZ3;

    // ---- prologue: group-0 scales plain-loaded & retired before the ledger
    sS0 = __float_as_uint(scales[ngl2]);
    sS1 = __float_as_uint(scales[ngl2 + 16]);
    sS2 = __float_as_uint(scales[ngl2 + 32]);
    sS3 = __float_as_uint(scales[ngl2 + 48]);
    sZ0 = (unsigned)qzeros[(ngl2 >> 3) + 0];
    sZ1 = (unsigned)qzeros[(ngl2 >> 3) + 2];
    sZ2 = (unsigned)qzeros[(ngl2 >> 3) + 4];
    sZ3 = (unsigned)qzeros[(ngl2 >> 3) + 6];
    asm volatile("" : "+v"(sS0), "+v"(sS1), "+v"(sS2), "+v"(sS3),
                      "+v"(sZ0), "+v"(sZ1), "+v"(sZ2), "+v"(sZ3));
    VMW(0);
    // ledger: qa(t0)[8], A(0)[4], qb(t1)[8], A(1)[4]  -> 24 outstanding
    ISSUE_Q8(qa0, qa1, qa2, qa3, qa4, qa5, qa6, qa7);   // tile 0
    ISSUE_A(aR, 0);
    ISSUE_Q8(qb0, qb1, qb2, qb3, qb4, qb5, qb6, qb7);   // tile 1
    ISSUE_A(aW, 1);
    VMW(12);                     // retire qa[8]+A(0)[4]; leaves qb[8]+A(1)[4]
    BAR();

    // ---- main loop: u = 0..30, tiles (2u, 2u+1); issues for 2u+2, 2u+3
    for (int u = 0; u < 31; ++u) {
        const int t0 = 2 * u;
        CVT_S();                                 // group u (raw retired)
        // ===== even tile t0, phase kh0 =====
        FRAGS(aR, 0);
        BAR();
        DQ4(qa0, qa1, qa2, qa3);                 // VALU under ds latency
        LGKM0();
        MFMA32();
        BAR();
        // ===== even tile t0, phase kh1 =====
        FRAGS(aR, 1);
        BAR();
        DQ4(qa4, qa5, qa6, qa7);
        ISSUE_Q8(qa0, qa1, qa2, qa3, qa4, qa5, qa6, qa7);   // tile t0+2
        ISSUE_SZ();                                          // group u+1
        LGKM0();
        MFMA32();
        VMW(12);                 // retire qb(t0+1)[8]+A(t0+1)[4] (tile-old)
        BAR();
        SWAP_A();
        ISSUE_A(aW, t0 + 2);
        // ===== odd tile t0+1, phase kh0 =====
        FRAGS(aR, 0);
        BAR();
        DQ4(qb0, qb1, qb2, qb3);
        LGKM0();
        MFMA32();
        BAR();
        // ===== odd tile t0+1, phase kh1 =====
        FRAGS(aR, 1);
        BAR();
        DQ4(qb4, qb5, qb6, qb7);
        ISSUE_Q8(qb0, qb1, qb2, qb3, qb4, qb5, qb6, qb7);   // tile t0+3
        LGKM0();
        MFMA32();
        VMW(8);                  // retire qa(t0+2)[8]+SZ[8]+A(t0+2)[4]
        BAR();
        SWAP_A();
        ISSUE_A(aW, t0 + 3);
    }

    // ---- tail: tiles 62, 63 (outstanding: qb(63)[8] + A(63)[4])
    CVT_S();                                     // group 31
    // tile 62
    FRAGS(aR, 0); BAR();
    DQ4(qa0, qa1, qa2, qa3);
    LGKM0(); MFMA32(); BAR();
    FRAGS(aR, 1); BAR();
    DQ4(qa4, qa5, qa6, qa7);
    LGKM0(); MFMA32();
    VMW(0);                      // drain qb(63) + A(63)
    BAR();
    SWAP_A();
    // tile 63
    FRAGS(aR, 0); BAR();
    DQ4(qb0, qb1, qb2, qb3);
    LGKM0(); MFMA32(); BAR();
    FRAGS(aR, 1); BAR();
    DQ4(qb4, qb5, qb6, qb7);
    LGKM0(); MFMA32();

    // ---- epilogue: C row=(lane>>4)*4+j, col=lane&15 (m89 layout)
    const int crow0 = (lane >> 4) << 2, ccol = lane & 15;
#pragma unroll
    for (int n = 0; n < 4; ++n) {
        const int col = bn0 + wc + n * 16 + ccol;
        const float bv = bias[col];
#pragma unroll
        for (int m = 0; m < 8; ++m) {
            const int row = bm0 + wr + m * 16 + crow0;
#pragma unroll
            for (int j = 0; j < 4; ++j)
                out[(size_t)(row + j) * N_DIM + col] = acc[m][n][j] + bv;
        }
    }
}

// ---------------- fallback (ws too small): proven r8 kernel ----------------
typedef __bf16 bf16x8 __attribute__((ext_vector_type(8)));

__global__ __launch_bounds__(256, 2)
void r18_fb(const float* __restrict__ x,
            const int*   __restrict__ qweight,
            const int*   __restrict__ qzeros,
            const float* __restrict__ scales,
            const float* __restrict__ bias,
            float* __restrict__ out)
{
    __shared__ __align__(16) unsigned char Asm[128 * 64 * 2];
    __shared__ __align__(16) unsigned char Bsm[128 * 64 * 2];
    const int tid = threadIdx.x, lane = tid & 63, wv = tid >> 6;
    const int wr = (wv >> 1) * 64, wc = (wv & 1) * 64;
    int bid = blockIdx.x;
    const int cpx = gridDim.x >> 3;
    bid = (bid & 7) * cpx + (bid >> 3);
    const int bm0 = (bid / 86) * 128, bn0 = (bid % 86) * 128;
    const int ar = tid >> 4, ac4 = tid & 15;
    const float* xp = x + (size_t)(bm0 + ar) * K_DIM + ac4 * 4;
    unsigned char* aw = Asm + ar * 128 + ((ac4 * 8) ^ ((ar & 7) << 4));
    const int bnn = tid & 127, bk8q = tid >> 7, ngl = bn0 + bnn;
    const int* qwp = qweight + (size_t)bk8q * N_DIM + ngl;
    unsigned char* bw = Bsm + bnn * 128;
    const int bsw = bnn & 7;
    const int frow = lane & 15, kb8 = lane >> 4, fsw = frow & 7;
    f32x4 acc[4][4];
#pragma unroll
    for (int m = 0; m < 4; ++m)
#pragma unroll
        for (int n = 0; n < 4; ++n) acc[m][n] = (f32x4){0.f, 0.f, 0.f, 0.f};
    float sc = 0.f, nsz = 0.f;
    for (int kt = 0; kt < K_DIM / 64; ++kt) {
        const int k0 = kt * 64;
        if ((k0 & 127) == 0) {
            const int g = k0 >> 7;
            sc = scales[(size_t)g * N_DIM + ngl];
            const unsigned zq = (unsigned)qzeros[(size_t)g * NZ8 + (ngl >> 3)];
            nsz = -sc * (float)((zq >> ((ngl & 7) * 4)) & 15u);
        }
#pragma unroll
        for (int i = 0; i < 8; ++i) {
            const float4 v = *(const float4*)(xp + (size_t)i * 16 * K_DIM + k0);
            union { __bf16 h[4]; unsigned long long u; } p;
            p.h[0] = (__bf16)v.x; p.h[1] = (__bf16)v.y;
            p.h[2] = (__bf16)v.z; p.h[3] = (__bf16)v.w;
            *(unsigned long long*)(aw + i * 16 * 128) = p.u;
        }
#pragma unroll
        for (int i = 0; i < 4; ++i) {
            const int k8 = 2 * i + bk8q;
            const unsigned q = (unsigned)qwp[(size_t)(kt * 8 + 2 * i) * N_DIM];
            union { __bf16 h[8]; bf16x8 v8; } p;
#pragma unroll
            for (int j = 0; j < 8; ++j)
                p.h[j] = (__bf16)__builtin_fmaf(sc, (float)((q >> (4 * j)) & 15u), nsz);
            *(bf16x8*)(bw + ((k8 ^ bsw) << 4)) = p.v8;
        }
        __syncthreads();
#pragma unroll
        for (int kh = 0; kh < 2; ++kh) {
            const int ksl = (kh << 2) + kb8;
            bf16x8 a2[4], b2[4];
#pragma unroll
            for (int m = 0; m < 4; ++m)
                a2[m] = *(const bf16x8*)(Asm + (wr + m * 16 + frow) * 128 + ((ksl ^ fsw) << 4));
#pragma unroll
            for (int n = 0; n < 4; ++n)
                b2[n] = *(const bf16x8*)(Bsm + (wc + n * 16 + frow) * 128 + ((ksl ^ fsw) << 4));
#pragma unroll
            for (int m = 0; m < 4; ++m)
#pragma unroll
                for (int n = 0; n < 4; ++n)
                    acc[m][n] = __builtin_amdgcn_mfma_f32_16x16x32_bf16(a2[m], b2[n], acc[m][n], 0, 0, 0);
        }
        __syncthreads();
    }
    const int crow0 = (lane >> 4) << 2, ccol = lane & 15;
#pragma unroll
    for (int n = 0; n < 4; ++n) {
        const int col = bn0 + wc + n * 16 + ccol;
        const float bv = bias[col];
#pragma unroll
        for (int m = 0; m < 4; ++m) {
            const int row = bm0 + wr + m * 16 + crow0;
#pragma unroll
            for (int j = 0; j < 4; ++j)
                out[(size_t)(row + j) * N_DIM + col] = acc[m][n][j] + bv;
        }
    }
}

extern "C" void kernel_launch(void* const* d_in, const int* in_sizes, int n_in,
                              void* d_out, int out_size, void* d_ws, size_t ws_size,
                              hipStream_t stream)
{
    const float* x   = (const float*)d_in[0];
    const int*   qw  = (const int*)d_in[1];
    const int*   qz  = (const int*)d_in[2];
    const float* scl = (const float*)d_in[3];
    const float* bs  = (const float*)d_in[4];
    float* out = (float*)d_out;

    const int M = in_sizes[0] / K_DIM;               // 4096
    const size_t xh_bytes = (size_t)M * K_DIM * 2;   // 33.6 MB

    if (ws_size >= xh_bytes) {
        __half* xh = (__half*)d_ws;
        const int nchunks = M * K_DIM / 8;
        hipLaunchKernelGGL(r18_xcvt, dim3(2048), dim3(256), 0, stream, x, xh, nchunks);
        dim3 grid((M / BM) * NT_N);                  // 688
        hipLaunchKernelGGL(r18_gemm, grid, dim3(512), 0, stream,
                           xh, qw, qz, scl, bs, out);
    } else {
        dim3 grid((M / 128) * 86);                   // 2752
        hipLaunchKernelGGL(r18_fb, grid, dim3(256), 0, stream,
                           x, qw, qz, scl, bs, out);
    }
}

// Round 19
// 403.210 us; speedup vs baseline: 1.0542x; 1.0542x over previous
//
#include <hip/hip_runtime.h>
#include <hip/hip_fp16.h>

#define K_DIM 4096
#define N_DIM 11008
#define NZ8   1376          // N_DIM/8
#define BM    256
#define BN    256
#define NT_N  43            // N_DIM/BN
#define NKT   64            // K_DIM/64
#define ATB   32768         // A tile bytes = 256*64*2

typedef _Float16 f16x8 __attribute__((ext_vector_type(8)));
typedef float    f32x4 __attribute__((ext_vector_type(4)));

#define SB()    __builtin_amdgcn_sched_barrier(0)
#define BAR()   __builtin_amdgcn_s_barrier()
#define VMW(N)  do { asm volatile("s_waitcnt vmcnt(" #N ")" ::: "memory"); SB(); } while (0)

// 1 int32 -> 8 fp16 dequant, (k,k+4)-interleaved order
__device__ __forceinline__ f16x8 dq8(unsigned q, __half2 scp, __half2 nzp)
{
    const unsigned mu = 0xE400E400u;
    const __half2 m1024 = *(const __half2*)&mu;
    union { __half2 h2[4]; f16x8 v; } p;
#pragma unroll
    for (int d = 0; d < 4; ++d) {
        unsigned t = ((q >> (4 * d)) & 0x000F000Fu) | 0x64006400u;
        p.h2[d] = __hfma2(__hadd2(*(const __half2*)&t, m1024), scp, nzp);
    }
    return p.v;
}

// ---- pre-pass: x f32 -> fp16 ws, layout [mtile][ktile][kh][slot][row][16B]
// (identical to r13/r15; GEMM A-stage = linear global_load_lds, conflict-free)
__global__ __launch_bounds__(256)
void r19_xcvt(const float* __restrict__ x, __half* __restrict__ xh, int nchunks)
{
    int c = blockIdx.x * 256 + threadIdx.x;
    const int stride = gridDim.x * 256;
    for (; c < nchunks; c += stride) {
        const int row = c & 255;
        const int sl  = (c >> 8) & 3;
        const int kh  = (c >> 10) & 1;
        const int tl  = c >> 11;
        const int mt  = tl >> 6;
        const int kt  = tl & 63;
        const size_t gm = (size_t)mt * 256 + row;
        const int kb = kt * 64 + kh * 32 + sl * 8;
        const float4 f0 = *(const float4*)(x + gm * K_DIM + kb);
        const float4 f1 = *(const float4*)(x + gm * K_DIM + kb + 4);
        union { __half2 h2[4]; int4 v; } p;
        p.h2[0] = __floats2half2_rn(f0.x, f1.x);
        p.h2[1] = __floats2half2_rn(f0.y, f1.y);
        p.h2[2] = __floats2half2_rn(f0.z, f1.z);
        p.h2[3] = __floats2half2_rn(f0.w, f1.w);
        ((int4*)xh)[c] = p.v;
    }
}

// ---- ledger issue helpers (r13/r15-proven 64-bit-vaddr asm form) ----
#define ISSUE_Q8(D0,D1,D2,D3,D4,D5,D6,D7) do { \
    asm volatile( \
        "global_load_dword %0, %8, off\n\t" \
        "global_load_dword %1, %8, off offset:64\n\t" \
        "global_load_dword %2, %8, off offset:128\n\t" \
        "global_load_dword %3, %8, off offset:192\n\t" \
        "global_load_dword %4, %9, off\n\t" \
        "global_load_dword %5, %9, off offset:64\n\t" \
        "global_load_dword %6, %9, off offset:128\n\t" \
        "global_load_dword %7, %9, off offset:192" \
        : "=&v"(D0), "=&v"(D1), "=&v"(D2), "=&v"(D3), \
          "=&v"(D4), "=&v"(D5), "=&v"(D6), "=&v"(D7) \
        : "v"(qp0), "v"(qp1) : "memory"); \
    qp0 += 8 * N_DIM; qp1 += 8 * N_DIM; \
} while (0)

#define ISSUE_SZ() do { \
    asm volatile( \
        "global_load_dword %0, %8, off\n\t" \
        "global_load_dword %1, %8, off offset:64\n\t" \
        "global_load_dword %2, %8, off offset:128\n\t" \
        "global_load_dword %3, %8, off offset:192\n\t" \
        "global_load_dword %4, %9, off\n\t" \
        "global_load_dword %5, %9, off offset:8\n\t" \
        "global_load_dword %6, %9, off offset:16\n\t" \
        "global_load_dword %7, %9, off offset:24" \
        : "=&v"(sS0), "=&v"(sS1), "=&v"(sS2), "=&v"(sS3), \
          "=&v"(sZ0), "=&v"(sZ1), "=&v"(sZ2), "=&v"(sZ3) \
        : "v"(sp), "v"(zp) : "memory"); \
    sp += N_DIM; zp += NZ8; \
} while (0)

#define ISSUE_A(BUFP, T) do { \
    const char* _s = agp + (size_t)(T) * ATB; \
    _Pragma("unroll") for (int j = 0; j < 4; ++j) \
        __builtin_amdgcn_global_load_lds((const unsigned int*)(_s + j * 8192), \
            (unsigned int*)((BUFP) + j * 8192 + tid * 16), 16, 0, 0); \
} while (0)

// issue 4 A-fragments (half an m-range of one kh) -> register bank
#define FRISS(BUFP, KH, MH, DEST) do { \
    _Pragma("unroll") for (int i = 0; i < 4; ++i) \
        DEST[i] = *(const f16x8*)((BUFP) + (KH) * 16384 + aOff + (MH) * 1024 + i * 256); \
    SB(); \
} while (0)

#define DQ4(Q0,Q1,Q2,Q3) do { \
    bf[0] = dq8(Q0, scp0, nzp0); bf[1] = dq8(Q1, scp1, nzp1); \
    bf[2] = dq8(Q2, scp2, nzp2); bf[3] = dq8(Q3, scp3, nzp3); \
} while (0)

// 16-MFMA cluster: 4 m-frags x 4 n
#define MFMA16(AF) do { \
    __builtin_amdgcn_s_setprio(1); \
    _Pragma("unroll") for (int m = 0; m < 4; ++m) \
        _Pragma("unroll") for (int n = 0; n < 4; ++n) \
            accp[m][n] = __builtin_amdgcn_mfma_f32_16x16x32_f16(AF[m], bf[n], accp[m][n], 0, 0, 0); \
    __builtin_amdgcn_s_setprio(0); \
    SB(); \
} while (0)

#define CVT_S() do { \
    const float _s0 = __uint_as_float(sS0), _s1 = __uint_as_float(sS1); \
    const float _s2 = __uint_as_float(sS2), _s3 = __uint_as_float(sS3); \
    const __half _h0 = __float2half_rn(_s0), _h1 = __float2half_rn(_s1); \
    const __half _h2 = __float2half_rn(_s2), _h3 = __float2half_rn(_s3); \
    scp0 = __half2(_h0, _h0); scp1 = __half2(_h1, _h1); \
    scp2 = __half2(_h2, _h2); scp3 = __half2(_h3, _h3); \
    const __half _n0 = __float2half_rn(-_s0 * (float)((sZ0 >> sh4) & 15u)); \
    const __half _n1 = __float2half_rn(-_s1 * (float)((sZ1 >> sh4) & 15u)); \
    const __half _n2 = __float2half_rn(-_s2 * (float)((sZ2 >> sh4) & 15u)); \
    const __half _n3 = __float2half_rn(-_s3 * (float)((sZ3 >> sh4) & 15u)); \
    nzp0 = __half2(_n0, _n0); nzp1 = __half2(_n1, _n1); \
    nzp2 = __half2(_n2, _n2); nzp3 = __half2(_n3, _n3); \
} while (0)

#define SWAP_A() do { unsigned char* _tp = aR; aR = aW; aW = _tp; } while (0)

// one K-tile body: 4 pipelined {FRISS | DQ | MFMA16} clusters.
// accL = acc rows 0-3 (m0-3), accH = rows 4-7 (m4-7).
// QL0..3 / QH0..3 = q dwords for kh0 / kh1.
#define TILE_CORE(QL0,QL1,QL2,QL3,QH0,QH1,QH2,QH3) do { \
    FRISS(aR, 0, 1, afB);  DQ4(QL0, QL1, QL2, QL3); \
    { auto& accp = accL; MFMA16(afA); } \
    FRISS(aR, 1, 0, afA); \
    { auto& accp = accH; MFMA16(afB); } \
    FRISS(aR, 1, 1, afB);  DQ4(QH0, QH1, QH2, QH3); \
    { auto& accp = accL; MFMA16(afA); } \
} while (0)
// ...followed by (after barrier/swap): FRISS(aR,0,0,afA); {accH; MFMA16(afB);}

// ---- fused GEMM: 256x256, 8 waves (2Mx4N), MFMA 16x16x32, B dequant-to-reg.
// r19 = r15 dataflow + ledger, tile body re-banked: two 4-frag A banks,
// each 16-MFMA cluster covers the next cluster's ds-read issue; last cluster
// of each tile runs after the barrier on registers, covering the next tile's
// first ds issue. Same register footprint as r15 (~248 unified).
__global__ __launch_bounds__(512, 2)
void r19_gemm(const __half* __restrict__ xh,
              const int*   __restrict__ qweight,
              const int*   __restrict__ qzeros,
              const float* __restrict__ scales,
              const float* __restrict__ bias,
              float* __restrict__ out)
{
    __shared__ __align__(16) unsigned char A0s[ATB], A1s[ATB];   // 64 KB

    const int tid  = threadIdx.x;
    const int lane = tid & 63;
    const int wid  = tid >> 6;
    const int wr   = (wid >> 2) * 128;   // wave M offset (0,128)
    const int wc   = (wid & 3) * 64;     // wave N offset (0,64,128,192)

    int bid = blockIdx.x;                // XCD swizzle (688 = 8*86)
    const int cpx = gridDim.x >> 3;
    bid = (bid & 7) * cpx + (bid >> 3);
    const int bm0 = (bid / NT_N) * BM;
    const int bn0 = (bid % NT_N) * BN;

    const int frow = lane & 15, kb8 = lane >> 4;
    const int ngl2 = bn0 + wc + frow;            // this lane's base column
    const int sh4  = (ngl2 & 7) * 4;
    const int aOff = kb8 * 4096 + (wr + frow) * 16;

    const char* agp = (const char*)xh + ((size_t)(bm0 >> 8) * NKT) * ATB + tid * 16;

    const int*   qp0 = qweight + (size_t)kb8 * N_DIM + ngl2;          // kh0 rows
    const int*   qp1 = qweight + (size_t)(kb8 + 4) * N_DIM + ngl2;    // kh1 rows
    const float* sp  = scales + (size_t)N_DIM + ngl2;                 // group 1
    const int*   zp  = qzeros + (size_t)NZ8 + (ngl2 >> 3);            // group 1

    unsigned char *aR = A0s, *aW = A1s;

    f32x4 accL[4][4], accH[4][4];
#pragma unroll
    for (int m = 0; m < 4; ++m)
#pragma unroll
        for (int n = 0; n < 4; ++n) {
            accL[m][n] = (f32x4){0.f, 0.f, 0.f, 0.f};
            accH[m][n] = (f32x4){0.f, 0.f, 0.f, 0.f};
        }
    f16x8 afA[4], afB[4], bf[4];
    __half2 scp0, scp1, scp2, scp3, nzp0, nzp1, nzp2, nzp3;
    unsigned qa0, qa1, qa2, qa3, qa4, qa5, qa6, qa7;
    unsigned qb0, qb1, qb2, qb3, qb4, qb5, qb6, qb7;
    unsigned sS0, sS1, sS2, sS3, sZ0, sZ1, sZ2, sZ3;

    // ---- prologue: group-0 scales plain-loaded & retired before the ledger
    sS0 = __float_as_uint(scales[ngl2]);
    sS1 = __float_as_uint(scales[ngl2 + 16]);
    sS2 = __float_as_uint(scales[ngl2 + 32]);
    sS3 = __float_as_uint(scales[ngl2 + 48]);
    sZ0 = (unsigned)qzeros[(ngl2 >> 3) + 0];
    sZ1 = (unsigned)qzeros[(ngl2 >> 3) + 2];
    sZ2 = (unsigned)qzeros[(ngl2 >> 3) + 4];
    sZ3 = (unsigned)qzeros[(ngl2 >> 3) + 6];
    asm volatile("" : "+v"(sS0), "+v"(sS1), "+v"(sS2), "+v"(sS3),
                      "+v"(sZ0), "+v"(sZ1), "+v"(sZ2), "+v"(sZ3));
    VMW(0);
    // ledger: qa(t0)[8], A(0)[4], qb(t1)[8], A(1)[4]  -> 24 outstanding
    ISSUE_Q8(qa0, qa1, qa2, qa3, qa4, qa5, qa6, qa7);   // tile 0
    ISSUE_A(aR, 0);
    ISSUE_Q8(qb0, qb1, qb2, qb3, qb4, qb5, qb6, qb7);   // tile 1
    ISSUE_A(aW, 1);
    VMW(12);                     // retire qa[8]+A(0)[4]; leaves qb[8]+A(1)[4]
    BAR();
    FRISS(aR, 0, 0, afA);        // tile 0, kh0, m0-3

    // ---- main loop: u = 0..30, tiles (2u, 2u+1); issues for 2u+2, 2u+3
    for (int u = 0; u < 31; ++u) {
        const int t0 = 2 * u;
        CVT_S();                                 // group u (raw retired)
        // ===== even tile t0 =====
        TILE_CORE(qa0, qa1, qa2, qa3, qa4, qa5, qa6, qa7);
        ISSUE_Q8(qa0, qa1, qa2, qa3, qa4, qa5, qa6, qa7);   // tile t0+2
        ISSUE_SZ();                                          // group u+1
        SB();
        VMW(16);                 // retire qb(t0+1)[8]+A(t0+1)[4] exactly
        BAR();
        SWAP_A();
        ISSUE_A(aW, t0 + 2); SB();
        FRISS(aR, 0, 0, afA);                    // tile t0+1, kh0, m0-3
        { auto& accp = accH; MFMA16(afB); }      // tile t0 last cluster
        // ===== odd tile t0+1 =====
        TILE_CORE(qb0, qb1, qb2, qb3, qb4, qb5, qb6, qb7);
        ISSUE_Q8(qb0, qb1, qb2, qb3, qb4, qb5, qb6, qb7);   // tile t0+3
        SB();
        VMW(8);                  // retire qa(t0+2)[8]+SZ[8]+A(t0+2)[4]
        BAR();
        SWAP_A();
        ISSUE_A(aW, t0 + 3); SB();
        FRISS(aR, 0, 0, afA);                    // tile t0+2, kh0, m0-3
        { auto& accp = accH; MFMA16(afB); }      // tile t0+1 last cluster
    }

    // ---- tail: tiles 62, 63 (outstanding: qb(63)[8] + A(63)[4])
    CVT_S();                                     // group 31
    // tile 62
    TILE_CORE(qa0, qa1, qa2, qa3, qa4, qa5, qa6, qa7);
    VMW(0);                      // drain qb(63) + A(63)
    BAR();
    SWAP_A();
    FRISS(aR, 0, 0, afA);
    { auto& accp = accH; MFMA16(afB); }
    // tile 63
    TILE_CORE(qb0, qb1, qb2, qb3, qb4, qb5, qb6, qb7);
    { auto& accp = accH; MFMA16(afB); }

    // ---- epilogue: C row=(lane>>4)*4+j, col=lane&15 (m89 layout)
    const int crow0 = (lane >> 4) << 2, ccol = lane & 15;
#pragma unroll
    for (int n = 0; n < 4; ++n) {
        const int col = bn0 + wc + n * 16 + ccol;
        const float bv = bias[col];
#pragma unroll
        for (int m = 0; m < 4; ++m) {
            const int rowL = bm0 + wr + m * 16 + crow0;
            const int rowH = rowL + 64;
#pragma unroll
            for (int j = 0; j < 4; ++j) {
                out[(size_t)(rowL + j) * N_DIM + col] = accL[m][n][j] + bv;
                out[(size_t)(rowH + j) * N_DIM + col] = accH[m][n][j] + bv;
            }
        }
    }
}

// ---------------- fallback (ws too small): proven r8 kernel ----------------
typedef __bf16 bf16x8 __attribute__((ext_vector_type(8)));

__global__ __launch_bounds__(256, 2)
void r19_fb(const float* __restrict__ x,
            const int*   __restrict__ qweight,
            const int*   __restrict__ qzeros,
            const float* __restrict__ scales,
            const float* __restrict__ bias,
            float* __restrict__ out)
{
    __shared__ __align__(16) unsigned char Asm[128 * 64 * 2];
    __shared__ __align__(16) unsigned char Bsm[128 * 64 * 2];
    const int tid = threadIdx.x, lane = tid & 63, wv = tid >> 6;
    const int wr = (wv >> 1) * 64, wc = (wv & 1) * 64;
    int bid = blockIdx.x;
    const int cpx = gridDim.x >> 3;
    bid = (bid & 7) * cpx + (bid >> 3);
    const int bm0 = (bid / 86) * 128, bn0 = (bid % 86) * 128;
    const int ar = tid >> 4, ac4 = tid & 15;
    const float* xp = x + (size_t)(bm0 + ar) * K_DIM + ac4 * 4;
    unsigned char* aw = Asm + ar * 128 + ((ac4 * 8) ^ ((ar & 7) << 4));
    const int bnn = tid & 127, bk8q = tid >> 7, ngl = bn0 + bnn;
    const int* qwp = qweight + (size_t)bk8q * N_DIM + ngl;
    unsigned char* bw = Bsm + bnn * 128;
    const int bsw = bnn & 7;
    const int frow = lane & 15, kb8 = lane >> 4, fsw = frow & 7;
    f32x4 acc[4][4];
#pragma unroll
    for (int m = 0; m < 4; ++m)
#pragma unroll
        for (int n = 0; n < 4; ++n) acc[m][n] = (f32x4){0.f, 0.f, 0.f, 0.f};
    float sc = 0.f, nsz = 0.f;
    for (int kt = 0; kt < K_DIM / 64; ++kt) {
        const int k0 = kt * 64;
        if ((k0 & 127) == 0) {
            const int g = k0 >> 7;
            sc = scales[(size_t)g * N_DIM + ngl];
            const unsigned zq = (unsigned)qzeros[(size_t)g * NZ8 + (ngl >> 3)];
            nsz = -sc * (float)((zq >> ((ngl & 7) * 4)) & 15u);
        }
#pragma unroll
        for (int i = 0; i < 8; ++i) {
            const float4 v = *(const float4*)(xp + (size_t)i * 16 * K_DIM + k0);
            union { __bf16 h[4]; unsigned long long u; } p;
            p.h[0] = (__bf16)v.x; p.h[1] = (__bf16)v.y;
            p.h[2] = (__bf16)v.z; p.h[3] = (__bf16)v.w;
            *(unsigned long long*)(aw + i * 16 * 128) = p.u;
        }
#pragma unroll
        for (int i = 0; i < 4; ++i) {
            const int k8 = 2 * i + bk8q;
            const unsigned q = (unsigned)qwp[(size_t)(kt * 8 + 2 * i) * N_DIM];
            union { __bf16 h[8]; bf16x8 v8; } p;
#pragma unroll
            for (int j = 0; j < 8; ++j)
                p.h[j] = (__bf16)__builtin_fmaf(sc, (float)((q >> (4 * j)) & 15u), nsz);
            *(bf16x8*)(bw + ((k8 ^ bsw) << 4)) = p.v8;
        }
        __syncthreads();
#pragma unroll
        for (int kh = 0; kh < 2; ++kh) {
            const int ksl = (kh << 2) + kb8;
            bf16x8 a2[4], b2[4];
#pragma unroll
            for (int m = 0; m < 4; ++m)
                a2[m] = *(const bf16x8*)(Asm + (wr + m * 16 + frow) * 128 + ((ksl ^ fsw) << 4));
#pragma unroll
            for (int n = 0; n < 4; ++n)
                b2[n] = *(const bf16x8*)(Bsm + (wc + n * 16 + frow) * 128 + ((ksl ^ fsw) << 4));
#pragma unroll
            for (int m = 0; m < 4; ++m)
#pragma unroll
                for (int n = 0; n < 4; ++n)
                    acc[m][n] = __builtin_amdgcn_mfma_f32_16x16x32_bf16(a2[m], b2[n], acc[m][n], 0, 0, 0);
        }
        __syncthreads();
    }
    const int crow0 = (lane >> 4) << 2, ccol = lane & 15;
#pragma unroll
    for (int n = 0; n < 4; ++n) {
        const int col = bn0 + wc + n * 16 + ccol;
        const float bv = bias[col];
#pragma unroll
        for (int m = 0; m < 4; ++m) {
            const int row = bm0 + wr + m * 16 + crow0;
#pragma unroll
            for (int j = 0; j < 4; ++j)
                out[(size_t)(row + j) * N_DIM + col] = acc[m][n][j] + bv;
        }
    }
}

extern "C" void kernel_launch(void* const* d_in, const int* in_sizes, int n_in,
                              void* d_out, int out_size, void* d_ws, size_t ws_size,
                              hipStream_t stream)
{
    const float* x   = (const float*)d_in[0];
    const int*   qw  = (const int*)d_in[1];
    const int*   qz  = (const int*)d_in[2];
    const float* scl = (const float*)d_in[3];
    const float* bs  = (const float*)d_in[4];
    float* out = (float*)d_out;

    const int M = in_sizes[0] / K_DIM;               // 4096
    const size_t xh_bytes = (size_t)M * K_DIM * 2;   // 33.6 MB

    if (ws_size >= xh_bytes) {
        __half* xh = (__half*)d_ws;
        const int nchunks = M * K_DIM / 8;
        hipLaunchKernelGGL(r19_xcvt, dim3(2048), dim3(256), 0, stream, x, xh, nchunks);
        dim3 grid((M / BM) * NT_N);                  // 688
        hipLaunchKernelGGL(r19_gemm, grid, dim3(512), 0, stream,
                           xh, qw, qz, scl, bs, out);
    } else {
        dim3 grid((M / 128) * 86);                   // 2752
        hipLaunchKernelGGL(r19_fb, grid, dim3(256), 0, stream,
                           x, qw, qz, scl, bs, out);
    }
}